// Round 18
// baseline (210.983 us; speedup 1.0000x reference)
//
#include <hip/hip_runtime.h>

#define M_DIM 64
#define K_DIM 8192
#define N_DIM 10240
#define KSPLIT 4
#define KBLK (K_DIM / KSPLIT)    // 2048 k per block
#define KSTEP 128                 // k per LDS chunk (ints)
#define NGRAN (KBLK / 256)        // 8 granules of 2 chunks
#define NTILE 64                  // n cols per block (4 waves x 16)
#define BUFB (NTILE * KSTEP * 2)  // bytes per LDS buffer half (16 KB)

typedef __attribute__((ext_vector_type(8))) short short8;
typedef __attribute__((ext_vector_type(4))) float f32x4;
typedef __attribute__((ext_vector_type(4))) int i32x4;

// exact for integer-valued floats |v| <= 127
static __device__ __forceinline__ ushort f2bf_trunc(float f) {
    return (ushort)(__float_as_uint(f) >> 16);
}

// ---------------- Kernel 1: per-token dynamic int8 quantization ----------------
// (verbatim — verified; + zeroes the 160 split-K counters each launch)
__global__ __launch_bounds__(256) void quant_kernel(
    const float* __restrict__ x,
    ushort* __restrict__ xq,
    float* __restrict__ xscale,
    uint* __restrict__ cnt) {
    const int m = blockIdx.x;
    const int tid = threadIdx.x;
    if (m == 0 && tid < N_DIM / NTILE) cnt[tid] = 0;  // reset fixup counters
    const float4* xrow = (const float4*)(x + m * K_DIM);
    float4 c[8];
    float mx = 0.f;
#pragma unroll
    for (int i = 0; i < 8; ++i) {
        c[i] = xrow[i * 256 + tid];
        mx = fmaxf(mx, fmaxf(fmaxf(fabsf(c[i].x), fabsf(c[i].y)),
                             fmaxf(fabsf(c[i].z), fabsf(c[i].w))));
    }
#pragma unroll
    for (int off = 32; off; off >>= 1) mx = fmaxf(mx, __shfl_xor(mx, off));
    __shared__ float wmax[4];
    if ((tid & 63) == 0) wmax[tid >> 6] = mx;
    __syncthreads();
    mx = fmaxf(fmaxf(wmax[0], wmax[1]), fmaxf(wmax[2], wmax[3]));
    const float s = mx / 127.0f;
    if (tid == 0) xscale[m] = s;

    ushort4* qrow = (ushort4*)(xq + m * K_DIM);
#pragma unroll
    for (int i = 0; i < 8; ++i) {
        float q0 = fminf(fmaxf(rintf(c[i].x / s), -127.f), 127.f);
        float q1 = fminf(fmaxf(rintf(c[i].y / s), -127.f), 127.f);
        float q2 = fminf(fmaxf(rintf(c[i].z / s), -127.f), 127.f);
        float q3 = fminf(fmaxf(rintf(c[i].w / s), -127.f), 127.f);
        ushort4 o;
        o.x = f2bf_trunc(q0);
        o.y = f2bf_trunc(q1);
        o.z = f2bf_trunc(q2);
        o.w = f2bf_trunc(q3);
        qrow[i * 256 + tid] = o;
    }
}

// ---------------- Kernel 2: r17 pipeline + split-K fixup epilogue --------------
// grid (160, 4), 4 waves, 64 KB LDS -> 2 blocks/CU. Pipeline verbatim r17.
// Epilogue: store partials, device-fence, per-n-tile arrival counter; the
// LAST of the 4 K-split blocks sums the partials in fixed order, applies
// xscale*wscale+bias, and writes the output tile (bit-identical to the old
// reduce_kernel, deterministic). The partials re-read overlaps other blocks'
// W streaming instead of running as a serial kernel afterwards.
__global__ __launch_bounds__(256, 2) void gemm_kernel(
    const ushort* __restrict__ xq,   // bf16 bits [64, 8192]
    const int* __restrict__ W,       // int32 [10240, 8192], |v| <= 127
    float* __restrict__ partials,    // f32 [KSPLIT][64][10240]
    uint* __restrict__ cnt,          // [160] arrival counters (pre-zeroed)
    const float* __restrict__ xscale,
    const float* __restrict__ wscale,
    const float* __restrict__ bias,
    float* __restrict__ out) {
    const int tid = threadIdx.x;
    const int w = tid >> 6;
    const int lane = tid & 63;
    const int r16 = lane & 15;
    const int kgrp = lane >> 4;
    const int n0 = blockIdx.x * NTILE;
    const int kb = blockIdx.y;
    const int k0 = kb * KBLK;

    __shared__ __align__(16) ushort Abuf[2][NTILE * KSTEP];  // 2 x 16 KB
    __shared__ __align__(16) ushort Bbuf[2][NTILE * KSTEP];  // 2 x 16 KB
    __shared__ uint arrival;

    i32x4 aB[16];   // W granule: 16 instrs x 1KB-contiguous (one row x 256 ints)
    short8 aA[8];   // A granule: 8 instrs x 1KB (2 rows x 256 ushorts)

#define ISSUE_B2(g)                                                            \
    {                                                                          \
        const int* base = W + k0 + (g) * 256 + lane * 4;                       \
        _Pragma("unroll") for (int i = 0; i < 16; ++i) {                       \
            aB[i] = __builtin_nontemporal_load(                                \
                (const i32x4*)(base + (size_t)(n0 + w * 16 + i) * K_DIM));     \
        }                                                                      \
    }
#define ISSUE_A2(g)                                                            \
    {                                                                          \
        const ushort* base = xq + k0 + (g) * 256 + (lane & 31) * 8;            \
        _Pragma("unroll") for (int i = 0; i < 8; ++i) {                        \
            const int row = w * 16 + i * 2 + (lane >> 5);                      \
            aA[i] = *(const short8*)(base + row * K_DIM);                      \
        }                                                                      \
    }
#define WRITE_B2()                                                             \
    {                                                                          \
        char* bb = (char*)&Bbuf[0][0] + (lane >> 5) * BUFB;                    \
        _Pragma("unroll") for (int i = 0; i < 16; ++i) {                       \
            const int row = w * 16 + i;                                        \
            ushort4 h;                                                         \
            h.x = f2bf_trunc((float)aB[i][0]);                                 \
            h.y = f2bf_trunc((float)aB[i][1]);                                 \
            h.z = f2bf_trunc((float)aB[i][2]);                                 \
            h.w = f2bf_trunc((float)aB[i][3]);                                 \
            const int off = ((lane & 31) * 8) ^ ((row & 7) << 4);              \
            *(ushort4*)(bb + row * 256 + off) = h;                             \
        }                                                                      \
    }
#define WRITE_A2()                                                             \
    {                                                                          \
        char* ab = (char*)&Abuf[0][0] + ((lane & 31) >> 4) * BUFB;             \
        _Pragma("unroll") for (int i = 0; i < 8; ++i) {                        \
            const int row = w * 16 + i * 2 + (lane >> 5);                      \
            const int off = ((lane & 15) * 16) ^ ((row & 7) << 4);             \
            *(short8*)(ab + row * 256 + off) = aA[i];                          \
        }                                                                      \
    }
#define COMPUTE(bufi)                                                          \
    {                                                                          \
        _Pragma("unroll") for (int ks = 0; ks < 4; ++ks) {                     \
            const int swz = (ks * 64 + kgrp * 16) ^ ((r16 & 7) << 4);          \
            short8 bfrag = *(const short8*)(                                   \
                (char*)&Bbuf[bufi][(w * 16 + r16) * KSTEP] + swz);             \
            _Pragma("unroll") for (int mt = 0; mt < 4; ++mt) {                 \
                short8 afrag = *(const short8*)(                               \
                    (char*)&Abuf[bufi][(mt * 16 + r16) * KSTEP] + swz);        \
                acc[mt] = __builtin_amdgcn_mfma_f32_16x16x32_bf16(             \
                    afrag, bfrag, acc[mt], 0, 0, 0);                           \
            }                                                                  \
        }                                                                      \
    }

    f32x4 acc[4];
#pragma unroll
    for (int i = 0; i < 4; ++i) acc[i] = (f32x4){0.f, 0.f, 0.f, 0.f};

    // granule 0 prologue
    ISSUE_B2(0)
    ISSUE_A2(0)
    WRITE_B2()
    WRITE_A2()
    __syncthreads();
    ISSUE_B2(1)
    ISSUE_A2(1)
    COMPUTE(0)
    COMPUTE(1)
    __syncthreads();

    // granules 1 .. NGRAN-2: steady state
#pragma unroll
    for (int g = 1; g < NGRAN - 1; ++g) {
        WRITE_B2()
        WRITE_A2()
        ISSUE_B2(g + 1)
        ISSUE_A2(g + 1)
        __syncthreads();
        COMPUTE(0)
        COMPUTE(1)
        __syncthreads();
    }

    // final granule
    WRITE_B2()
    WRITE_A2()
    __syncthreads();
    COMPUTE(0)
    COMPUTE(1)

    // epilogue 1: C via LDS for coalesced partials write (verbatim r17)
    __syncthreads();
    float* Cl = (float*)&Abuf[0][0];  // [64 m][64 n] f32 = 16 KB
#pragma unroll
    for (int mt = 0; mt < 4; ++mt)
#pragma unroll
        for (int j = 0; j < 4; ++j)
            Cl[(mt * 16 + kgrp * 4 + j) * 64 + w * 16 + r16] = acc[mt][j];
    __syncthreads();
    float* pb = partials + (size_t)kb * (M_DIM * N_DIM);
#pragma unroll
    for (int i = 0; i < 4; ++i) {
        const int idx = tid + 256 * i;
        const int m = idx >> 4;
        const int ch = idx & 15;
        *(f32x4*)(pb + m * N_DIM + n0 + ch * 4) = ((const f32x4*)Cl)[idx];
    }

    // epilogue 2: split-K fixup — last block of this n-tile reduces.
    __threadfence();              // release: my partials visible device-wide
    __syncthreads();              // all threads' stores fenced
    if (tid == 0) arrival = atomicAdd(&cnt[blockIdx.x], 1u);
    __syncthreads();
    if (arrival == KSPLIT - 1) {  // last arriving K-split block
        __threadfence();          // acquire: see siblings' partials
#pragma unroll
        for (int i = 0; i < 4; ++i) {
            const int idx = tid + 256 * i;  // (m, 16B-chunk) within tile
            const int m = idx >> 4;
            const int ch = idx & 15;
            const size_t o = (size_t)m * N_DIM + n0 + ch * 4;
            f32x4 s = *(const f32x4*)(partials + o);
#pragma unroll
            for (int p = 1; p < KSPLIT; ++p)
                s += *(const f32x4*)(partials + (size_t)p * (M_DIM * N_DIM) + o);
            f32x4 ws = *(const f32x4*)(wscale + n0 + ch * 4);
            f32x4 bs = *(const f32x4*)(bias + n0 + ch * 4);
            *(f32x4*)(out + o) = s * xscale[m] * ws + bs;
        }
    }
#undef ISSUE_B2
#undef ISSUE_A2
#undef WRITE_A2
#undef WRITE_B2
#undef COMPUTE
}

extern "C" void kernel_launch(void* const* d_in, const int* in_sizes, int n_in,
                              void* d_out, int out_size, void* d_ws, size_t ws_size,
                              hipStream_t stream) {
    const float* x = (const float*)d_in[0];
    const int* W = (const int*)d_in[1];
    const float* wscale = (const float*)d_in[2];
    const float* bias = (const float*)d_in[3];
    float* out = (float*)d_out;

    float* xscale = (float*)d_ws;                       // 256 B
    uint* cnt = (uint*)((char*)d_ws + 1024);            // 640 B counters
    ushort* xq = (ushort*)((char*)d_ws + 4096);         // 1 MB
    float* partials = (float*)((char*)d_ws + 2097152);  // 10.5 MB

    quant_kernel<<<M_DIM, 256, 0, stream>>>(x, xq, xscale, cnt);
    gemm_kernel<<<dim3(N_DIM / NTILE, KSPLIT), 256, 0, stream>>>(
        xq, W, partials, cnt, xscale, wscale, bias, out);
}

// Round 20
// 80.423 us; speedup vs baseline: 2.6234x; 2.6234x over previous
//
#include <hip/hip_runtime.h>

#define M_DIM 64
#define K_DIM 8192
#define N_DIM 10240
#define KSPLIT 4
#define KBLK (K_DIM / KSPLIT)    // 2048 k per block
#define KSTEP 128                 // k per LDS chunk (ints)
#define NGRAN (KBLK / 256)        // 8 granules of 2 chunks
#define NTILE 64                  // n cols per block (4 waves x 16)
#define BUFB (NTILE * KSTEP * 2)  // bytes per LDS buffer half (16 KB)

typedef __attribute__((ext_vector_type(8))) short short8;
typedef __attribute__((ext_vector_type(4))) float f32x4;
typedef __attribute__((ext_vector_type(4))) int i32x4;

// exact for integer-valued floats |v| <= 127
static __device__ __forceinline__ ushort f2bf_trunc(float f) {
    return (ushort)(__float_as_uint(f) >> 16);
}

// ---------------- Kernel 1: per-token dynamic int8 quantization ----------------
// widened to 1024 threads/block (64 blocks were 0.25/CU, latency-bound);
// same verified math, 16-wave reduce tree; NT loads via ext_vector f32x4
// (HIP float4 is rejected by __builtin_nontemporal_load).
__global__ __launch_bounds__(1024) void quant_kernel(
    const float* __restrict__ x,
    ushort* __restrict__ xq,
    float* __restrict__ xscale) {
    const int m = blockIdx.x;
    const int tid = threadIdx.x;
    const f32x4* xrow = (const f32x4*)(x + m * K_DIM);  // 2048 x f32x4
    f32x4 c[2];
    float mx = 0.f;
#pragma unroll
    for (int i = 0; i < 2; ++i) {
        c[i] = __builtin_nontemporal_load(xrow + i * 1024 + tid);
        mx = fmaxf(mx, fmaxf(fmaxf(fabsf(c[i][0]), fabsf(c[i][1])),
                             fmaxf(fabsf(c[i][2]), fabsf(c[i][3]))));
    }
#pragma unroll
    for (int off = 32; off; off >>= 1) mx = fmaxf(mx, __shfl_xor(mx, off));
    __shared__ float wmax[16];
    if ((tid & 63) == 0) wmax[tid >> 6] = mx;
    __syncthreads();
#pragma unroll
    for (int i = 0; i < 16; ++i) mx = fmaxf(mx, wmax[i]);
    const float s = mx / 127.0f;  // matches reference x_scale exactly
    if (tid == 0) xscale[m] = s;

    ushort4* qrow = (ushort4*)(xq + m * K_DIM);
#pragma unroll
    for (int i = 0; i < 2; ++i) {
        float q0 = fminf(fmaxf(rintf(c[i][0] / s), -127.f), 127.f);
        float q1 = fminf(fmaxf(rintf(c[i][1] / s), -127.f), 127.f);
        float q2 = fminf(fmaxf(rintf(c[i][2] / s), -127.f), 127.f);
        float q3 = fminf(fmaxf(rintf(c[i][3] / s), -127.f), 127.f);
        ushort4 o;
        o.x = f2bf_trunc(q0);
        o.y = f2bf_trunc(q1);
        o.z = f2bf_trunc(q2);
        o.w = f2bf_trunc(q3);
        qrow[i * 1024 + tid] = o;
    }
}

// ---------------- Kernel 2: granule-paired LDS pipeline + NT W stream ----------
// (verbatim — verified r16/r17 structure, KSPLIT=4)
__global__ __launch_bounds__(256, 2) void gemm_kernel(
    const ushort* __restrict__ xq,   // bf16 bits [64, 8192]
    const int* __restrict__ W,       // int32 [10240, 8192], |v| <= 127
    float* __restrict__ partials) {  // f32 [KSPLIT][64][10240]
    const int tid = threadIdx.x;
    const int w = tid >> 6;
    const int lane = tid & 63;
    const int r16 = lane & 15;
    const int kgrp = lane >> 4;
    const int n0 = blockIdx.x * NTILE;
    const int kb = blockIdx.y;
    const int k0 = kb * KBLK;

    __shared__ __align__(16) ushort Abuf[2][NTILE * KSTEP];  // 2 x 16 KB
    __shared__ __align__(16) ushort Bbuf[2][NTILE * KSTEP];  // 2 x 16 KB

    i32x4 aB[16];   // W granule: 16 instrs x 1KB-contiguous (one row x 256 ints)
    short8 aA[8];   // A granule: 8 instrs x 1KB (2 rows x 256 ushorts)

#define ISSUE_B2(g)                                                            \
    {                                                                          \
        const int* base = W + k0 + (g) * 256 + lane * 4;                       \
        _Pragma("unroll") for (int i = 0; i < 16; ++i) {                       \
            aB[i] = __builtin_nontemporal_load(                                \
                (const i32x4*)(base + (size_t)(n0 + w * 16 + i) * K_DIM));     \
        }                                                                      \
    }
#define ISSUE_A2(g)                                                            \
    {                                                                          \
        const ushort* base = xq + k0 + (g) * 256 + (lane & 31) * 8;            \
        _Pragma("unroll") for (int i = 0; i < 8; ++i) {                        \
            const int row = w * 16 + i * 2 + (lane >> 5);                      \
            aA[i] = *(const short8*)(base + row * K_DIM);                      \
        }                                                                      \
    }
#define WRITE_B2()                                                             \
    {                                                                          \
        char* bb = (char*)&Bbuf[0][0] + (lane >> 5) * BUFB;                    \
        _Pragma("unroll") for (int i = 0; i < 16; ++i) {                       \
            const int row = w * 16 + i;                                        \
            ushort4 h;                                                         \
            h.x = f2bf_trunc((float)aB[i][0]);                                 \
            h.y = f2bf_trunc((float)aB[i][1]);                                 \
            h.z = f2bf_trunc((float)aB[i][2]);                                 \
            h.w = f2bf_trunc((float)aB[i][3]);                                 \
            const int off = ((lane & 31) * 8) ^ ((row & 7) << 4);              \
            *(ushort4*)(bb + row * 256 + off) = h;                             \
        }                                                                      \
    }
#define WRITE_A2()                                                             \
    {                                                                          \
        char* ab = (char*)&Abuf[0][0] + ((lane & 31) >> 4) * BUFB;             \
        _Pragma("unroll") for (int i = 0; i < 8; ++i) {                        \
            const int row = w * 16 + i * 2 + (lane >> 5);                      \
            const int off = ((lane & 15) * 16) ^ ((row & 7) << 4);             \
            *(short8*)(ab + row * 256 + off) = aA[i];                          \
        }                                                                      \
    }
#define COMPUTE(bufi)                                                          \
    {                                                                          \
        _Pragma("unroll") for (int ks = 0; ks < 4; ++ks) {                     \
            const int swz = (ks * 64 + kgrp * 16) ^ ((r16 & 7) << 4);          \
            short8 bfrag = *(const short8*)(                                   \
                (char*)&Bbuf[bufi][(w * 16 + r16) * KSTEP] + swz);             \
            _Pragma("unroll") for (int mt = 0; mt < 4; ++mt) {                 \
                short8 afrag = *(const short8*)(                               \
                    (char*)&Abuf[bufi][(mt * 16 + r16) * KSTEP] + swz);        \
                acc[mt] = __builtin_amdgcn_mfma_f32_16x16x32_bf16(             \
                    afrag, bfrag, acc[mt], 0, 0, 0);                           \
            }                                                                  \
        }                                                                      \
    }

    f32x4 acc[4];
#pragma unroll
    for (int i = 0; i < 4; ++i) acc[i] = (f32x4){0.f, 0.f, 0.f, 0.f};

    // granule 0 prologue
    ISSUE_B2(0)
    ISSUE_A2(0)
    WRITE_B2()
    WRITE_A2()
    __syncthreads();
    ISSUE_B2(1)
    ISSUE_A2(1)
    COMPUTE(0)
    COMPUTE(1)
    __syncthreads();

    // granules 1 .. NGRAN-2: steady state
#pragma unroll
    for (int g = 1; g < NGRAN - 1; ++g) {
        WRITE_B2()
        WRITE_A2()
        ISSUE_B2(g + 1)
        ISSUE_A2(g + 1)
        __syncthreads();
        COMPUTE(0)
        COMPUTE(1)
        __syncthreads();
    }

    // final granule
    WRITE_B2()
    WRITE_A2()
    __syncthreads();
    COMPUTE(0)
    COMPUTE(1)

    // epilogue: C via LDS for coalesced partials write (verbatim)
    __syncthreads();
    float* Cl = (float*)&Abuf[0][0];  // [64 m][64 n] f32 = 16 KB
#pragma unroll
    for (int mt = 0; mt < 4; ++mt)
#pragma unroll
        for (int j = 0; j < 4; ++j)
            Cl[(mt * 16 + kgrp * 4 + j) * 64 + w * 16 + r16] = acc[mt][j];
    __syncthreads();
    float* pb = partials + (size_t)kb * (M_DIM * N_DIM);
#pragma unroll
    for (int i = 0; i < 4; ++i) {
        const int idx = tid + 256 * i;
        const int m = idx >> 4;
        const int ch = idx & 15;
        *(f32x4*)(pb + m * N_DIM + n0 + ch * 4) = ((const f32x4*)Cl)[idx];
    }
#undef ISSUE_B2
#undef ISSUE_A2
#undef WRITE_A2
#undef WRITE_B2
#undef COMPUTE
}

// ---------------- Kernel 3: split-K reduce + dequant + bias --------------------
// (verbatim r17 + NT loads on read-once partials)
__global__ __launch_bounds__(256) void reduce_kernel(
    const float* __restrict__ partials,
    const float* __restrict__ xscale,
    const float* __restrict__ wscale,
    const float* __restrict__ bias,
    float* __restrict__ out) {
    const int idx = blockIdx.x * 256 + threadIdx.x;  // 0 .. 64*2560-1
    const int m = idx / (N_DIM / 4);
    const int c = idx - m * (N_DIM / 4);
    const f32x4* P = (const f32x4*)partials;
    f32x4 s = (f32x4){0.f, 0.f, 0.f, 0.f};
#pragma unroll
    for (int p = 0; p < KSPLIT; ++p)
        s += __builtin_nontemporal_load(P + ((size_t)p * M_DIM + m) * (N_DIM / 4) + c);
    f32x4 ws = ((const f32x4*)wscale)[c];
    f32x4 bs = ((const f32x4*)bias)[c];
    const float xs = xscale[m];
    ((f32x4*)out)[idx] = s * xs * ws + bs;
}

extern "C" void kernel_launch(void* const* d_in, const int* in_sizes, int n_in,
                              void* d_out, int out_size, void* d_ws, size_t ws_size,
                              hipStream_t stream) {
    const float* x = (const float*)d_in[0];
    const int* W = (const int*)d_in[1];
    const float* wscale = (const float*)d_in[2];
    const float* bias = (const float*)d_in[3];
    float* out = (float*)d_out;

    float* xscale = (float*)d_ws;                       // 256 B
    ushort* xq = (ushort*)((char*)d_ws + 4096);         // 1 MB
    float* partials = (float*)((char*)d_ws + 2097152);  // 10.5 MB

    quant_kernel<<<M_DIM, 1024, 0, stream>>>(x, xq, xscale);
    gemm_kernel<<<dim3(N_DIM / NTILE, KSPLIT), 256, 0, stream>>>(xq, W, partials);
    reduce_kernel<<<(M_DIM * N_DIM / 4) / 256, 256, 0, stream>>>(
        partials, xscale, wscale, bias, out);
}